// Round 4
// baseline (426.010 us; speedup 1.0000x reference)
//
#include <hip/hip_runtime.h>
#include <math.h>

#define NH 16
#define NKV 8
#define HDIM 128
#define SEQ 2048
#define DMODEL 2048

typedef int   v4i __attribute__((ext_vector_type(4)));
typedef float v4f __attribute__((ext_vector_type(4)));
typedef __bf16 v8bf __attribute__((ext_vector_type(8)));

static constexpr float SM_SCALE = 0.08838834764831843f; // 128**-0.5

#define GLOBP(p) (__attribute__((address_space(1))) void*)(p)
#define LDSP(p)  (__attribute__((address_space(3))) void*)(p)
#define ASYNC16(g, l) __builtin_amdgcn_global_load_lds(GLOBP(g), LDSP(l), 16, 0, 0)

// ---------------- per-row symmetric int8 quant: int8 out + scale ----------------
__global__ __launch_bounds__(256) void row_quant_k(const float* __restrict__ in,
        signed char* __restrict__ out, float* __restrict__ scale, int cols) {
    int row = blockIdx.x;
    const float4* x4 = (const float4*)(in + (size_t)row * cols);
    unsigned int* op = (unsigned int*)(out + (size_t)row * cols);
    int n4 = cols >> 2;
    int tid = threadIdx.x;
    float amax = 0.f;
    for (int c = tid; c < n4; c += 256) {
        float4 v = x4[c];
        amax = fmaxf(amax, fmaxf(fmaxf(fabsf(v.x), fabsf(v.y)),
                                 fmaxf(fabsf(v.z), fabsf(v.w))));
    }
#pragma unroll
    for (int m = 32; m; m >>= 1) amax = fmaxf(amax, __shfl_xor(amax, m));
    __shared__ float red[4];
    if ((tid & 63) == 0) red[tid >> 6] = amax;
    __syncthreads();
    float a = fmaxf(fmaxf(red[0], red[1]), fmaxf(red[2], red[3]));
    float s = fmaxf(a / 127.0f, 1e-8f);
    if (tid == 0) scale[row] = s;
    for (int c = tid; c < n4; c += 256) {
        float4 v = x4[c];
        int b0 = (int)fminf(fmaxf(rintf(v.x / s), -127.f), 127.f);
        int b1 = (int)fminf(fmaxf(rintf(v.y / s), -127.f), 127.f);
        int b2 = (int)fminf(fmaxf(rintf(v.z / s), -127.f), 127.f);
        int b3 = (int)fminf(fmaxf(rintf(v.w / s), -127.f), 127.f);
        op[c] = (b0 & 255) | ((b1 & 255) << 8) | ((b2 & 255) << 16) | ((b3 & 255) << 24);
    }
}

// ---------------- int8 GEMM: C[m,n] = sa[m]*sb[n]*sum_k qa[m,k]*qb[n,k] ----------------
__global__ __launch_bounds__(256) void gemm_i8_k(const signed char* __restrict__ A,
        const float* __restrict__ sa, const signed char* __restrict__ B,
        const float* __restrict__ sb, float* __restrict__ C, int M, int N, int K) {
    __shared__ __align__(16) signed char lsA[8192];
    __shared__ __align__(16) signed char lsB[8192];
    int tid = threadIdx.x;
    int w = tid >> 6, l = tid & 63;
    int wr = w >> 1, wc = w & 1;
    int lrow = l & 15, lk = (l >> 4) * 16;
    int m0 = blockIdx.y * 128, n0 = blockIdx.x * 128;
    v4i acc[4][4];
#pragma unroll
    for (int i = 0; i < 4; ++i)
#pragma unroll
        for (int j = 0; j < 4; ++j) acc[i][j] = (v4i){0, 0, 0, 0};

    for (int k0 = 0; k0 < K; k0 += 64) {
        __syncthreads();
#pragma unroll
        for (int a = 0; a < 2; ++a) {
            int f = a * 4 + w;
            ASYNC16(A + (size_t)(m0 + f * 16 + lrow) * K + k0 + lk, lsA + f * 1024);
            ASYNC16(B + (size_t)(n0 + f * 16 + lrow) * K + k0 + lk, lsB + f * 1024);
        }
        __syncthreads();
        v4i af[4], bf[4];
#pragma unroll
        for (int i = 0; i < 4; ++i) af[i] = *(const v4i*)(lsA + (wr * 4 + i) * 1024 + l * 16);
#pragma unroll
        for (int j = 0; j < 4; ++j) bf[j] = *(const v4i*)(lsB + (wc * 4 + j) * 1024 + l * 16);
#pragma unroll
        for (int i = 0; i < 4; ++i)
#pragma unroll
            for (int j = 0; j < 4; ++j)
                acc[i][j] = __builtin_amdgcn_mfma_i32_16x16x64_i8(af[i], bf[j], acc[i][j], 0, 0, 0);
    }
    int r0 = m0 + wr * 64, c0 = n0 + wc * 64;
    int lg = l >> 4;
    float sbv[4];
#pragma unroll
    for (int j = 0; j < 4; ++j) sbv[j] = sb[c0 + j * 16 + lrow];
#pragma unroll
    for (int i = 0; i < 4; ++i) {
        float4 s4 = *(const float4*)(sa + r0 + i * 16 + lg * 4);
        float sav[4] = {s4.x, s4.y, s4.z, s4.w};
#pragma unroll
        for (int j = 0; j < 4; ++j) {
#pragma unroll
            for (int reg = 0; reg < 4; ++reg) {
                int r = r0 + i * 16 + lg * 4 + reg;
                C[(size_t)r * N + c0 + j * 16 + lrow] = (float)acc[i][j][reg] * (sav[reg] * sbv[j]);
            }
        }
    }
}

// ---------------- rope cos/sin table: accurate sincosf, computed once ----------------
__global__ void rope_tab_k(const int* __restrict__ pos_ids,
                           float* __restrict__ ct, float* __restrict__ st) {
    int t = blockIdx.x;
    int fi = threadIdx.x; // 64
    float pw = (float)pow(1.0e6, (double)fi / 64.0);
    float inv = 1.0f / pw;
    float fr = (float)pos_ids[t] * inv;
    float sn, c;
    sincosf(fr, &sn, &c);
    ct[t * 64 + fi] = c;
    st[t * 64 + fi] = sn;
}

// ---------------- rmsnorm + rope; q/k -> int8 + scale, v -> dequantized fp32 ----------------
__global__ __launch_bounds__(128) void qkv_post_k(const float* __restrict__ q_lin,
        const float* __restrict__ k_lin, const float* __restrict__ v_lin,
        const float* __restrict__ qw, const float* __restrict__ kw,
        const float* __restrict__ ct, const float* __restrict__ st,
        signed char* __restrict__ q_i8, float* __restrict__ sq,
        signed char* __restrict__ k_i8, float* __restrict__ sk,
        float* __restrict__ v_dq) {
    int t = blockIdx.x;
    int hh = blockIdx.y;
    int d = threadIdx.x;
    __shared__ float xs[HDIM];
    __shared__ float red[2];
    float x;
    if (hh < NH)            x = q_lin[(size_t)t * DMODEL + hh * HDIM + d];
    else if (hh < NH + NKV) x = k_lin[(size_t)t * (NKV * HDIM) + (hh - NH) * HDIM + d];
    else                    x = v_lin[(size_t)t * (NKV * HDIM) + (hh - NH - NKV) * HDIM + d];

    if (hh < NH + NKV) {
        float sqv = x * x;
#pragma unroll
        for (int m = 32; m; m >>= 1) sqv += __shfl_xor(sqv, m);
        if ((d & 63) == 0) red[d >> 6] = sqv;
        __syncthreads();
        float mv = (red[0] + red[1]) / 128.0f;
        float rs = 1.0f / sqrtf(mv + 1e-6f);
        x = (x * rs) * ((hh < NH) ? qw[d] : kw[d]);
        xs[d] = x;
        __syncthreads();
        float other = (d < 64) ? xs[d + 64] : xs[d - 64];
        int fi = d & 63;
        float c = ct[t * 64 + fi];
        float sn = st[t * 64 + fi];
        x = (d < 64) ? (x * c - other * sn) : (x * c + other * sn);
        __syncthreads();
    }
    float amax = fabsf(x);
#pragma unroll
    for (int m = 32; m; m >>= 1) amax = fmaxf(amax, __shfl_xor(amax, m));
    if ((d & 63) == 0) red[d >> 6] = amax;
    __syncthreads();
    float s = fmaxf(fmaxf(red[0], red[1]) / 127.0f, 1e-8f);
    float qf = fminf(fmaxf(rintf(x / s), -127.f), 127.f);
    if (hh < NH) {
        q_i8[((size_t)hh * SEQ + t) * HDIM + d] = (signed char)(int)qf;
        if (d == 0) sq[hh * SEQ + t] = s;
    } else if (hh < NH + NKV) {
        k_i8[((size_t)(hh - NH) * SEQ + t) * HDIM + d] = (signed char)(int)qf;
        if (d == 0) sk[(hh - NH) * SEQ + t] = s;
    } else {
        v_dq[((size_t)(hh - NH - NKV) * SEQ + t) * HDIM + d] = qf * s;
    }
}

// ---------------- bf16 helpers ----------------
__device__ __forceinline__ unsigned short f2bf(float x) {
    unsigned int u = __float_as_uint(x);
    return (unsigned short)((u + 0x7fffu + ((u >> 16) & 1u)) >> 16);
}
__device__ __forceinline__ float bf2f(unsigned short h) {
    return __uint_as_float(((unsigned int)h) << 16);
}

// ---------------- V transpose + bf16 split ----------------
__global__ __launch_bounds__(256) void vt_split_k(const float* __restrict__ v_dq,
        unsigned short* __restrict__ vt_hi, unsigned short* __restrict__ vt_lo) {
    int kv = blockIdx.y, t0 = blockIdx.x * 64;
    __shared__ float tile[64][132];
    int tid = threadIdx.x;
    const float* src = v_dq + ((size_t)kv * SEQ + t0) * HDIM;
#pragma unroll
    for (int i = 0; i < 8; ++i) {
        int f4 = i * 256 + tid;
        int r = f4 >> 5, c = (f4 & 31) << 2;
        float4 v = *(const float4*)(src + r * HDIM + c);
        tile[r][c] = v.x; tile[r][c + 1] = v.y; tile[r][c + 2] = v.z; tile[r][c + 3] = v.w;
    }
    __syncthreads();
    int d = tid >> 1, th = (tid & 1) * 32;
    size_t obase = ((size_t)kv * HDIM + d) * SEQ + t0 + th;
#pragma unroll
    for (int j = 0; j < 32; j += 2) {
        float a = tile[th + j][d], b = tile[th + j + 1][d];
        unsigned short ah = f2bf(a), bh = f2bf(b);
        unsigned short al = f2bf(a - bf2f(ah)), bl = f2bf(b - bf2f(bh));
        *(unsigned int*)(vt_hi + obase + j) = (unsigned int)ah | ((unsigned int)bh << 16);
        *(unsigned int*)(vt_lo + obase + j) = (unsigned int)al | ((unsigned int)bl << 16);
    }
}

// ---------------- attention pass 1 (split-K): partial (m, Z) per row ----------------
// grid (32*4, 16): qb = bx>>2, chunk c = bx&3 (8 kb each). Lane-local online (m,Z);
// one cross-lane butterfly per chunk. No LDS.
__global__ __launch_bounds__(256, 4) void attn_p1_k(const signed char* __restrict__ q_i8,
        const float* __restrict__ sq, const signed char* __restrict__ k_i8,
        const float* __restrict__ sk, float* __restrict__ mz) {
    int bx = blockIdx.x, h = blockIdx.y, kvh = h >> 1;
    int qb = bx >> 2, c = bx & 3;
    int nch = (qb + 8) >> 3;            // ceil((qb+1)/8)
    if (c >= nch) return;
    int q0 = qb * 64;
    int kb0 = c * 8, kb1 = min((c + 1) * 8, qb + 1);
    int tid = threadIdx.x, w = tid >> 6, l = tid & 63;
    int lrow = l & 15, lg = l >> 4;

    const signed char* qrow = q_i8 + ((size_t)h * SEQ + q0 + w * 16 + lrow) * HDIM + lg * 16;
    v4i qf0 = *(const v4i*)(qrow);
    v4i qf1 = *(const v4i*)(qrow + 64);
    float4 s4 = *(const float4*)(sq + (size_t)h * SEQ + q0 + w * 16 + lg * 4);
    float sqr[4] = {s4.x, s4.y, s4.z, s4.w};
    const signed char* kbase = k_i8 + (size_t)kvh * SEQ * HDIM;
    const float* skb = sk + (size_t)kvh * SEQ;

    float m_l[4], z_l[4];
#pragma unroll
    for (int r = 0; r < 4; ++r) { m_l[r] = -1e30f; z_l[r] = 0.f; }

    v4i ka[8], kn[8];
    auto loadK = [&](v4i* dst, int k0) {
#pragma unroll
        for (int f = 0; f < 8; ++f) {
            int j = f >> 1, kk = f & 1;
            dst[f] = *(const v4i*)(kbase + (size_t)(k0 + j * 16 + lrow) * HDIM + kk * 64 + lg * 16);
        }
    };

    loadK(ka, kb0 * 64);
    for (int kb = kb0; kb < kb1; ++kb) {
        if (kb + 1 < kb1) loadK(kn, (kb + 1) * 64);
        int k0 = kb * 64;
        v4i sci[4];
#pragma unroll
        for (int j = 0; j < 4; ++j) {
            v4i z = {0, 0, 0, 0};
            v4i t0 = __builtin_amdgcn_mfma_i32_16x16x64_i8(qf0, ka[j * 2], z, 0, 0, 0);
            sci[j] = __builtin_amdgcn_mfma_i32_16x16x64_i8(qf1, ka[j * 2 + 1], t0, 0, 0, 0);
        }
        float skc[4];
#pragma unroll
        for (int j = 0; j < 4; ++j) skc[j] = skb[k0 + j * 16 + lrow];
#pragma unroll
        for (int reg = 0; reg < 4; ++reg) {
            int r = q0 + w * 16 + lg * 4 + reg;
            float s[4];
#pragma unroll
            for (int j = 0; j < 4; ++j) {
                float sv = ((float)sci[j][reg] * (sqr[reg] * skc[j])) * SM_SCALE;
                s[j] = (k0 + j * 16 + lrow <= r) ? sv : -1e30f;
            }
            float mt = fmaxf(fmaxf(s[0], s[1]), fmaxf(s[2], s[3]));
            float mn = fmaxf(m_l[reg], mt);
            float zt = 0.f;
#pragma unroll
            for (int j = 0; j < 4; ++j)
                zt += (s[j] > -5e29f) ? __expf(s[j] - mn) : 0.f;
            z_l[reg] = z_l[reg] * __expf(m_l[reg] - mn) + zt;
            m_l[reg] = mn;
        }
        if (kb + 1 < kb1) {
#pragma unroll
            for (int f = 0; f < 8; ++f) ka[f] = kn[f];
        }
    }
    // cross-lane (lrow) butterfly combine of (m, Z)
#pragma unroll
    for (int reg = 0; reg < 4; ++reg) {
#pragma unroll
        for (int mask = 1; mask <= 8; mask <<= 1) {
            float om = __shfl_xor(m_l[reg], mask);
            float oz = __shfl_xor(z_l[reg], mask);
            float mn = fmaxf(m_l[reg], om);
            z_l[reg] = z_l[reg] * __expf(m_l[reg] - mn) + oz * __expf(om - mn);
            m_l[reg] = mn;
        }
    }
    if (lrow == 0) {
        size_t base = ((size_t)(h * 32 + qb) * 4 + c) * 128;
#pragma unroll
        for (int reg = 0; reg < 4; ++reg) {
            *(float2*)&mz[base + (w * 16 + lg * 4 + reg) * 2] =
                make_float2(m_l[reg], z_l[reg]);
        }
    }
}

// ---------------- attention pass 2 (split-K PV) ----------------
// grid (32*2, 16): qb = bx>>1, chunk c = bx&1 (16 kb each; tiles qb<16 have 1 chunk).
// Prologue combines pass-1 partials -> final m, 1/Z, p-scale. c==0 writes attn2,
// c==1 writes fp32 partial (summed by attn_red_k).
__global__ __launch_bounds__(256, 2) void attn_p2_k(const signed char* __restrict__ q_i8,
        const float* __restrict__ sq, const signed char* __restrict__ k_i8,
        const float* __restrict__ sk, const unsigned short* __restrict__ vt_hi,
        const unsigned short* __restrict__ vt_lo, const float* __restrict__ mz,
        float* __restrict__ attn2, float* __restrict__ pp) {
    __shared__ __align__(16) unsigned short vlds[2][16384];
    __shared__ __align__(16) unsigned short plds[4096];
    int bx = blockIdx.x, h = blockIdx.y, kvh = h >> 1;
    int qb = bx >> 1, c = bx & 1;
    int nch2 = (qb >= 16) ? 2 : 1;
    if (c >= nch2) return;
    int q0 = qb * 64;
    int kb0 = c * 16, kb1 = min((c + 1) * 16, qb + 1);
    int tid = threadIdx.x, w = tid >> 6, l = tid & 63;
    int lrow = l & 15, lg = l >> 4;

    const signed char* qrow = q_i8 + ((size_t)h * SEQ + q0 + w * 16 + lrow) * HDIM + lg * 16;
    v4i qf0 = *(const v4i*)(qrow);
    v4i qf1 = *(const v4i*)(qrow + 64);
    float4 s4 = *(const float4*)(sq + (size_t)h * SEQ + q0 + w * 16 + lg * 4);
    float sqr[4] = {s4.x, s4.y, s4.z, s4.w};

    // combine pass-1 partials -> final m, zinv, spv, rsp for this thread's 4 rows
    int nch1 = (qb + 8) >> 3;
    float m_fin[4], zinv[4], spv[4], rsp[4];
#pragma unroll
    for (int reg = 0; reg < 4; ++reg) {
        int r = w * 16 + lg * 4 + reg;
        float M = -1e30f, Z = 0.f;
        for (int c1 = 0; c1 < nch1; ++c1) {
            float2 p = *(const float2*)&mz[((size_t)(h * 32 + qb) * 4 + c1) * 128 + r * 2];
            float mn = fmaxf(M, p.x);
            Z = Z * __expf(M - mn) + p.y * __expf(p.x - mn);
            M = mn;
        }
        m_fin[reg] = M;
        zinv[reg] = 1.0f / Z;
        spv[reg] = fmaxf(zinv[reg] / 127.0f, 1e-8f);
        rsp[reg] = 1.0f / spv[reg];
    }

    const signed char* kbase = k_i8 + (size_t)kvh * SEQ * HDIM;
    const float* skb = sk + (size_t)kvh * SEQ;
    const unsigned short* vhb = vt_hi + (size_t)kvh * HDIM * SEQ;
    const unsigned short* vlb = vt_lo + (size_t)kvh * HDIM * SEQ;

    v4i ka[8], kn[8];
    auto loadK = [&](v4i* dst, int k0) {
#pragma unroll
        for (int f = 0; f < 8; ++f) {
            int j = f >> 1, kk = f & 1;
            dst[f] = *(const v4i*)(kbase + (size_t)(k0 + j * 16 + lrow) * HDIM + kk * 64 + lg * 16);
        }
    };
    auto issueV = [&](int kb) {
        int k0 = kb * 64;
        unsigned short* vb = &vlds[kb & 1][0];
#pragma unroll
        for (int a = 0; a < 8; ++a) {
            int fv = a * 4 + w;
            int sp_ = fv >> 4, jd = (fv >> 1) & 7, kk2 = fv & 1;
            const unsigned short* vsrc = (sp_ ? vlb : vhb) +
                (size_t)(jd * 16 + lrow) * SEQ + k0 + kk2 * 32 + lg * 8;
            ASYNC16(vsrc, vb + fv * 512);
        }
    };

    v4f acco[8];
#pragma unroll
    for (int jd = 0; jd < 8; ++jd) acco[jd] = (v4f){0.f, 0.f, 0.f, 0.f};

    loadK(ka, kb0 * 64);
    issueV(kb0);
    asm volatile("s_waitcnt vmcnt(0)" ::: "memory");
    __syncthreads();
    for (int kb = kb0; kb < kb1; ++kb) {
        int k0 = kb * 64;
        if (kb + 1 < kb1) {
            issueV(kb + 1);
            loadK(kn, (kb + 1) * 64);
        }
        v4i sci[4];
#pragma unroll
        for (int j = 0; j < 4; ++j) {
            v4i z = {0, 0, 0, 0};
            v4i t0 = __builtin_amdgcn_mfma_i32_16x16x64_i8(qf0, ka[j * 2], z, 0, 0, 0);
            sci[j] = __builtin_amdgcn_mfma_i32_16x16x64_i8(qf1, ka[j * 2 + 1], t0, 0, 0, 0);
        }
        float skc[4];
#pragma unroll
        for (int j = 0; j < 4; ++j) skc[j] = skb[k0 + j * 16 + lrow];
#pragma unroll
        for (int reg = 0; reg < 4; ++reg) {
            int rq = lg * 4 + reg;
            int r = q0 + w * 16 + rq;
#pragma unroll
            for (int j = 0; j < 4; ++j) {
                int cc = j * 16 + lrow;
                float pd = 0.f;
                if (k0 + cc <= r) {
                    float sv = ((float)sci[j][reg] * (sqr[reg] * skc[j])) * SM_SCALE;
                    float p = __expf(sv - m_fin[reg]) * zinv[reg];
                    pd = fminf(rintf(p * rsp[reg]), 127.f);
                }
                plds[(w * 2 + (cc >> 5)) * 512 + (rq + 16 * ((cc >> 3) & 3)) * 8 + (cc & 7)] =
                    (unsigned short)(__float_as_uint(pd) >> 16);
            }
        }
        v8bf pf0 = *(const v8bf*)(plds + (w * 2 + 0) * 512 + l * 8);
        v8bf pf1 = *(const v8bf*)(plds + (w * 2 + 1) * 512 + l * 8);
        const unsigned short* vb = &vlds[kb & 1][0];
#pragma unroll
        for (int jd = 0; jd < 8; ++jd) {
            v8bf vh0 = *(const v8bf*)(vb + (jd * 2 + 0) * 512 + l * 8);
            v8bf vh1 = *(const v8bf*)(vb + (jd * 2 + 1) * 512 + l * 8);
            v8bf vl0 = *(const v8bf*)(vb + (16 + jd * 2 + 0) * 512 + l * 8);
            v8bf vl1 = *(const v8bf*)(vb + (16 + jd * 2 + 1) * 512 + l * 8);
            v4f t = acco[jd];
            t = __builtin_amdgcn_mfma_f32_16x16x32_bf16(pf0, vh0, t, 0, 0, 0);
            t = __builtin_amdgcn_mfma_f32_16x16x32_bf16(pf1, vh1, t, 0, 0, 0);
            t = __builtin_amdgcn_mfma_f32_16x16x32_bf16(pf0, vl0, t, 0, 0, 0);
            t = __builtin_amdgcn_mfma_f32_16x16x32_bf16(pf1, vl1, t, 0, 0, 0);
            acco[jd] = t;
        }
        asm volatile("s_waitcnt vmcnt(0)" ::: "memory");
        __syncthreads();
        if (kb + 1 < kb1) {
#pragma unroll
            for (int f = 0; f < 8; ++f) ka[f] = kn[f];
        }
    }
    if (c == 0) {
#pragma unroll
        for (int jd = 0; jd < 8; ++jd)
#pragma unroll
            for (int reg = 0; reg < 4; ++reg) {
                int r = q0 + w * 16 + lg * 4 + reg;
                attn2[(size_t)r * DMODEL + h * HDIM + jd * 16 + lrow] = acco[jd][reg] * spv[reg];
            }
    } else {
#pragma unroll
        for (int jd = 0; jd < 8; ++jd)
#pragma unroll
            for (int reg = 0; reg < 4; ++reg) {
                int rr = w * 16 + lg * 4 + reg;
                pp[(((size_t)h * 16 + (qb - 16)) * 64 + rr) * 128 + jd * 16 + lrow] =
                    acco[jd][reg] * spv[reg];
            }
    }
}

// ---------------- reduce: attn2 += chunk-1 partials (tiles qb>=16) ----------------
__global__ __launch_bounds__(256) void attn_red_k(float* __restrict__ attn2,
        const float* __restrict__ pp) {
    int t16 = blockIdx.x, h = blockIdx.y;
    int qb = t16 + 16;
    int tid = threadIdx.x;
    for (int e = tid; e < 2048; e += 256) {     // 2048 float4s = 64x128
        int i = (e * 4) >> 7, j = (e * 4) & 127;
        float4 p = *(const float4*)&pp[(((size_t)h * 16 + t16) * 64 + i) * 128 + j];
        float* d = &attn2[(size_t)(qb * 64 + i) * DMODEL + h * HDIM + j];
        float4 dv = *(float4*)d;
        dv.x += p.x; dv.y += p.y; dv.z += p.z; dv.w += p.w;
        *(float4*)d = dv;
    }
}

extern "C" void kernel_launch(void* const* d_in, const int* in_sizes, int n_in,
                              void* d_out, int out_size, void* d_ws, size_t ws_size,
                              hipStream_t stream) {
    (void)in_sizes; (void)n_in; (void)out_size; (void)ws_size;
    const float* hidden = (const float*)d_in[0];
    const float* Wq = (const float*)d_in[1];
    const float* Wk = (const float*)d_in[2];
    const float* Wv = (const float*)d_in[3];
    const float* Wo = (const float*)d_in[4];
    const float* qw = (const float*)d_in[5];
    const float* kw = (const float*)d_in[6];
    const int* pos = (const int*)d_in[7];
    float* out = (float*)d_out;
    char* ws = (char*)d_ws;

    const size_t MB = 1024 * 1024;
    signed char* x_i8  = (signed char*)(ws);            // 4 MB
    signed char* wq_i8 = (signed char*)(ws + 4 * MB);   // 4 MB
    signed char* wk_i8 = (signed char*)(ws + 8 * MB);   // 2 MB
    signed char* wv_i8 = (signed char*)(ws + 10 * MB);  // 2 MB
    signed char* wo_i8 = (signed char*)(ws + 12 * MB);  // 4 MB
    signed char* q_i8  = (signed char*)(ws + 16 * MB);  // 4 MB
    signed char* k_i8  = (signed char*)(ws + 20 * MB);  // 2 MB
    float* sx  = (float*)(ws + 22 * MB);
    float* swq = sx + 2048;
    float* swk = swq + 2048;
    float* swv = swk + 1024;
    float* swo = swv + 1024;
    float* sq  = swo + 2048;                            // 16*2048
    float* sk  = sq + NH * SEQ;                         // 8*2048
    float* sa  = sk + NKV * SEQ;                        // 2048
    float* ct  = (float*)(ws + 22 * MB + 512 * 1024);   // 512 KB
    float* st  = (float*)(ws + 22 * MB + 1024 * 1024);  // 512 KB
    float* q_lin = (float*)(ws + 24 * MB);              // 16 MB -> attn2
    float* k_lin = (float*)(ws + 40 * MB);              // 8 MB  -> pp (partials)
    float* v_lin = (float*)(ws + 48 * MB);              // 8 MB  -> vt_hi/vt_lo
    unsigned short* vt_hi = (unsigned short*)(ws + 48 * MB);
    unsigned short* vt_lo = (unsigned short*)(ws + 52 * MB);
    float* v_dq = (float*)(ws + 56 * MB);               // 8 MB  -> mz after vt_split
    float* mz   = (float*)(ws + 56 * MB);               // 1 MB (aliases dead v_dq)
    float* pp   = (float*)(ws + 40 * MB);               // 8 MB (aliases dead k_lin)
    float* attn2 = q_lin;
    signed char* a_i8 = x_i8;

    rope_tab_k<<<2048, 64, 0, stream>>>(pos, ct, st);
    row_quant_k<<<2048, 256, 0, stream>>>(hidden, x_i8, sx, 2048);
    row_quant_k<<<2048, 256, 0, stream>>>(Wq, wq_i8, swq, 2048);
    row_quant_k<<<1024, 256, 0, stream>>>(Wk, wk_i8, swk, 2048);
    row_quant_k<<<1024, 256, 0, stream>>>(Wv, wv_i8, swv, 2048);
    row_quant_k<<<2048, 256, 0, stream>>>(Wo, wo_i8, swo, 2048);

    gemm_i8_k<<<dim3(16, 16), 256, 0, stream>>>(x_i8, sx, wq_i8, swq, q_lin, 2048, 2048, 2048);
    gemm_i8_k<<<dim3(8, 16), 256, 0, stream>>>(x_i8, sx, wk_i8, swk, k_lin, 2048, 1024, 2048);
    gemm_i8_k<<<dim3(8, 16), 256, 0, stream>>>(x_i8, sx, wv_i8, swv, v_lin, 2048, 1024, 2048);

    qkv_post_k<<<dim3(2048, 32), 128, 0, stream>>>(q_lin, k_lin, v_lin, qw, kw, ct, st,
                                                   q_i8, sq, k_i8, sk, v_dq);
    vt_split_k<<<dim3(32, 8), 256, 0, stream>>>(v_dq, vt_hi, vt_lo);

    attn_p1_k<<<dim3(128, 16), 256, 0, stream>>>(q_i8, sq, k_i8, sk, mz);
    attn_p2_k<<<dim3(64, 16), 256, 0, stream>>>(q_i8, sq, k_i8, sk, vt_hi, vt_lo, mz,
                                                attn2, pp);
    attn_red_k<<<dim3(16, 16), 256, 0, stream>>>(attn2, pp);

    row_quant_k<<<2048, 256, 0, stream>>>(attn2, a_i8, sa, 2048);
    gemm_i8_k<<<dim3(16, 16), 256, 0, stream>>>(a_i8, sa, wo_i8, swo, out, 2048, 2048, 2048);
}